// Round 12
// baseline (144.985 us; speedup 1.0000x reference)
//
#include <hip/hip_runtime.h>
#include <cstdint>
#include <cstddef>

#define BB 128
#define VV 128000
#define TT 4096
#define NWIN 2048            // windows = 128 rows x 16 slices
#define WVR (VV / 16)        // 8000 tokens per window
#define WHW (WVR / 4)        // 2000 packed words
#define NT 256
#define EXC_CAP 96

typedef float vf4 __attribute__((ext_vector_type(4)));

// Round-22 = round-21 resubmitted verbatim (GPU acquisition timeout — the
// machine-level role split is unmeasured; holding the kernel fixed).
// Round-21: MACHINE-LEVEL role split. Measured ladder: r13 hist->stream 43.7;
// r16 stream->hist ~40; r20 wave-split ~41-44 (hist wave's serial path ~= the
// stream, barrier re-serialized). Lesson: intra-block overlap keeps failing.
// New: 4096 blocks, even = pure stream (no LDS/barrier, x4 unroll), odd =
// hist block computing FINAL exception values (penalty f(logits), boost
// logits+5*mult — pure functions of inputs) into d_ws per-window lists;
// tiny second kernel applies them (kernel-boundary ordering, no races).
// 4096 > resident capacity -> block replacement flow fills the straggler
// tail that showed as 36% occupancy.
// SENT = 0xFF7F0000 (finite bf16 0xFF7F) — r1/r2 lessons. RINV <=1 ulp.

__device__ __forceinline__ void win_decode(int id, int& b, int& vbase) {
  // XCD-aware swizzle: 16 windows of a row land on one XCD (gen L2 locality)
  const int xcd = id & 7, q = id >> 3, s = q & 15;
  b = (q >> 4) * 8 + xcd;
  vbase = s * WVR;
}

__device__ __forceinline__ int block_detect(const unsigned char* maskb,
                                            unsigned* det, int tid) {
  if (tid == 0) *det = 0u;
  __syncthreads();
  const uint4* md = (const uint4*)maskb;
  unsigned a = 0u, c = 0u;
#pragma unroll
  for (int k = 0; k < 4; ++k) {          // 256 threads x 4 uint4 = 16 KB scan
    uint4 w = md[tid + k * NT];
    unsigned o = w.x | w.y | w.z | w.w;
    a |= o & 0x000000FFu;
    c |= o & 0xFFFFFF00u;
  }
  unsigned long long ba = __ballot(a != 0u);
  unsigned long long bc = __ballot(c != 0u);
  if ((tid & 63) == 0) {
    unsigned bits = (ba ? 1u : 0u) | (bc ? 2u : 0u);
    if (bits) atomicOr(det, bits);
  }
  __syncthreads();
  return (*det == 3u) ? 1 : 3;   // u8 vs 32-bit word mode
}

template<int ML>
__global__ __launch_bounds__(NT) void enforce_fused(
    const float* __restrict__ logits,
    const int*  __restrict__ gen,
    const unsigned char* __restrict__ maskb,
    const int*  __restrict__ req,
    float* __restrict__ out,
    unsigned* __restrict__ wsc,       // [NWIN] exception counts
    uint2*    __restrict__ wse,       // [NWIN][EXC_CAP] {idx-in-window, bits(val)}
    int R)
{
  __shared__ unsigned hist[WHW];   // 8 KB (hist role only)
  __shared__ uint2 exc[EXC_CAP];
  __shared__ unsigned nexc;
  const int tid = threadIdx.x;
  const int L   = blockIdx.x;      // 4096
  const int id  = L >> 1;
  int b, vbase; win_decode(id, b, vbase);

  int ml = ML;
  if constexpr (ML == -1) {
    __shared__ unsigned det;
    ml = block_detect(maskb, &det, tid);
  }

  const float SENT = __uint_as_float(0xFF7F0000u);
  const float RINV = 1.0f / 1.2f;
  auto forb1 = [&](int t) -> bool {
    if (ml == 1) return maskb[t] != 0;
    return ((const int*)maskb)[t] != 0;   // i32 1 / f32 1.0f both nonzero
  };

  if ((L & 1) == 0) {
    // ================= STREAM ROLE: pure masked copy, x4 unroll =============
    const vf4* lrow = (const vf4*)(logits + (size_t)b * VV + vbase);
    vf4*       orow = (vf4*)(out + (size_t)b * VV + vbase);
    const unsigned* m8  = (const unsigned*)(maskb + vbase);
    const int4*     m32 = (const int4*)((const int*)maskb + vbase);
    auto lmask = [&](int i) -> unsigned {
      if (ml == 1) return m8[i];
      int4 m = m32[i];
      return (m.x ? 1u : 0u) | (m.y ? 0x100u : 0u) |
             (m.z ? 0x10000u : 0u) | (m.w ? 0x1000000u : 0u);
    };
    for (int i0 = tid; i0 < WHW; i0 += 4 * NT) {   // 2 outer iterations
      const int i1 = i0 + NT, i2 = i0 + 2 * NT, i3 = i0 + 3 * NT;
      const bool p1 = i1 < WHW, p2 = i2 < WHW, p3 = i3 < WHW;
      vf4 x0 = lrow[i0];           unsigned f0 = lmask(i0);
      vf4 x1 = {0,0,0,0}, x2 = {0,0,0,0}, x3 = {0,0,0,0};
      unsigned f1 = 0, f2 = 0, f3 = 0;
      if (p1) { x1 = lrow[i1]; f1 = lmask(i1); }
      if (p2) { x2 = lrow[i2]; f2 = lmask(i2); }
      if (p3) { x3 = lrow[i3]; f3 = lmask(i3); }
      vf4 r0, r1, r2, r3;
#pragma unroll
      for (int j = 0; j < 4; ++j) r0[j] = ((f0 >> (j*8)) & 0xFFu) ? SENT : x0[j];
      orow[i0] = r0;
      if (p1) {
#pragma unroll
        for (int j = 0; j < 4; ++j) r1[j] = ((f1 >> (j*8)) & 0xFFu) ? SENT : x1[j];
        orow[i1] = r1;
      }
      if (p2) {
#pragma unroll
        for (int j = 0; j < 4; ++j) r2[j] = ((f2 >> (j*8)) & 0xFFu) ? SENT : x2[j];
        orow[i2] = r2;
      }
      if (p3) {
#pragma unroll
        for (int j = 0; j < 4; ++j) r3[j] = ((f3 >> (j*8)) & 0xFFu) ? SENT : x3[j];
        orow[i3] = r3;
      }
    }
  } else {
    // ================= HIST ROLE: exceptions -> ws ==========================
    for (int i = tid; i < WHW; i += NT) hist[i] = 0u;
    if (tid == 0) nexc = 0u;
    __syncthreads();

    // gen scan; atomicAdd return catches the unique 2->3 transition.
    // Penalty value is a pure function of logits -> computable NOW.
    const int4* grow = (const int4*)(gen + b * TT);
    for (int i = tid; i < TT / 4; i += NT) {       // 4 iterations
      int4 g = grow[i];
      const int t4[4] = {g.x, g.y, g.z, g.w};
#pragma unroll
      for (int j = 0; j < 4; ++j) {
        const int t = t4[j];
        unsigned d = (unsigned)(t - vbase);
        if (d < (unsigned)WVR) {
          const unsigned sh = (d & 3u) * 8u;
          unsigned old = atomicAdd(&hist[d >> 2], 1u << sh);
          if (((old >> sh) & 0xFFu) == 2u && !forb1(t)) {
            float v  = logits[(size_t)b * VV + t];
            float pv = (v > 0.0f) ? v * RINV : v * 1.2f;
            unsigned k = atomicAdd(&nexc, 1u);
            if (k < EXC_CAP) exc[k] = make_uint2(d, __float_as_uint(pv));
          }
        }
      }
    }
    __syncthreads();   // cnt final before boost check

    // boosts: req tokens in-window, cnt==0, allowed. Dedup to first
    // occurrence; value = logits + 5*multiplicity (matches reference
    // duplicate scatter-add).
    for (int r = tid; r < R; r += NT) {
      const int t = req[r];
      unsigned d = (unsigned)(t - vbase);
      if (d < (unsigned)WVR) {
        bool first = true; int mult = 0;
        for (int j = 0; j < R; ++j) {
          if (req[j] == t) { if (j < r) first = false; ++mult; }
        }
        if (first) {
          unsigned cnt = (hist[d >> 2] >> ((d & 3u) * 8u)) & 0xFFu;
          if (cnt == 0u && !forb1(t)) {
            float v = logits[(size_t)b * VV + t] + 5.0f * (float)mult;
            unsigned k = atomicAdd(&nexc, 1u);
            if (k < EXC_CAP) exc[k] = make_uint2(d, __float_as_uint(v));
          }
        }
      }
    }
    __syncthreads();

    unsigned n = nexc < EXC_CAP ? nexc : EXC_CAP;
    if (tid == 0) wsc[id] = n;
    for (unsigned k = tid; k < n; k += NT)
      wse[(size_t)id * EXC_CAP + k] = exc[k];
  }
}

__global__ __launch_bounds__(NT) void apply_exc(
    float* __restrict__ out,
    const unsigned* __restrict__ wsc,
    const uint2* __restrict__ wse)
{
  const int w = blockIdx.x * NT + threadIdx.x;
  if (w >= NWIN) return;
  int b, vbase; win_decode(w, b, vbase);
  unsigned n = wsc[w]; if (n > EXC_CAP) n = EXC_CAP;
  const uint2* e = wse + (size_t)w * EXC_CAP;
  for (unsigned k = 0; k < n; ++k) {
    uint2 q = e[k];
    out[(size_t)b * VV + vbase + q.x] = __uint_as_float(q.y);
  }
}

// ---------------- fallback monolith (r16, measured 123.9 total) -------------
template<int ML>
__global__ __launch_bounds__(NT) void enforce_mono(
    const float* __restrict__ logits,
    const int*  __restrict__ gen,
    const unsigned char* __restrict__ maskb,
    const int*  __restrict__ req,
    float* __restrict__ out,
    int R)
{
  __shared__ unsigned hist[WHW];
  __shared__ int cand[64];
  __shared__ unsigned ncand;
  const int tid = threadIdx.x;
  int b, vbase; win_decode(blockIdx.x, b, vbase);

  int ml = ML;
  if constexpr (ML == -1) {
    __shared__ unsigned det;
    ml = block_detect(maskb, &det, tid);
  }
  for (int i = tid; i < WHW; i += NT) hist[i] = 0u;
  if (tid == 0) ncand = 0u;
  __syncthreads();

  const float SENT = __uint_as_float(0xFF7F0000u);
  const float RINV = 1.0f / 1.2f;
  auto forb1 = [&](int t) -> bool {
    if (ml == 1) return maskb[t] != 0;
    return ((const int*)maskb)[t] != 0;
  };
  const vf4* lrow = (const vf4*)(logits + (size_t)b * VV + vbase);
  vf4*       orow = (vf4*)(out + (size_t)b * VV + vbase);
  const unsigned* m8  = (const unsigned*)(maskb + vbase);
  const int4*     m32 = (const int4*)((const int*)maskb + vbase);
  auto lmask = [&](int i) -> unsigned {
    if (ml == 1) return m8[i];
    int4 m = m32[i];
    return (m.x ? 1u : 0u) | (m.y ? 0x100u : 0u) |
           (m.z ? 0x10000u : 0u) | (m.w ? 0x1000000u : 0u);
  };
  for (int i0 = tid; i0 < WHW; i0 += 2 * NT) {
    const int i1 = i0 + NT;
    const bool p1 = (i1 < WHW);
    vf4 x0 = lrow[i0]; unsigned f0 = lmask(i0);
    vf4 x1 = {0,0,0,0}; unsigned f1 = 0u;
    if (p1) { x1 = lrow[i1]; f1 = lmask(i1); }
    vf4 r0, r1;
#pragma unroll
    for (int j = 0; j < 4; ++j) r0[j] = ((f0 >> (j*8)) & 0xFFu) ? SENT : x0[j];
    orow[i0] = r0;
    if (p1) {
#pragma unroll
      for (int j = 0; j < 4; ++j) r1[j] = ((f1 >> (j*8)) & 0xFFu) ? SENT : x1[j];
      orow[i1] = r1;
    }
  }
  const int4* grow = (const int4*)(gen + b * TT);
  for (int i = tid; i < TT / 4; i += NT) {
    int4 g = grow[i];
    const int t4[4] = {g.x, g.y, g.z, g.w};
#pragma unroll
    for (int j = 0; j < 4; ++j) {
      const int t = t4[j];
      unsigned d = (unsigned)(t - vbase);
      if (d < (unsigned)WVR) {
        const unsigned sh = (d & 3u) * 8u;
        unsigned old = atomicAdd(&hist[d >> 2], 1u << sh);
        if (((old >> sh) & 0xFFu) == 2u) {
          unsigned k = atomicAdd(&ncand, 1u);
          if (k < 64u) cand[k] = t;
        }
      }
    }
  }
  __syncthreads();
  const unsigned nc = ncand < 64u ? ncand : 64u;
  for (unsigned k = tid; k < nc; k += NT) {
    const int t = cand[k];
    if (!forb1(t)) {
      float v = logits[(size_t)b * VV + t];
      out[(size_t)b * VV + t] = (v > 0.0f) ? v * RINV : v * 1.2f;
    }
  }
  for (int r = tid; r < R; r += NT) {
    const int t = req[r];
    unsigned d = (unsigned)(t - vbase);
    if (d < (unsigned)WVR) {
      unsigned cnt = (hist[d >> 2] >> ((d & 3u) * 8u)) & 0xFFu;
      if (cnt == 0u && !forb1(t))
        atomicAdd(out + (size_t)b * VV + t, 5.0f);
    }
  }
}

extern "C" void kernel_launch(void* const* d_in, const int* in_sizes, int n_in,
                              void* d_out, int out_size, void* d_ws, size_t ws_size,
                              hipStream_t stream) {
  const float* logits = (const float*)d_in[0];
  const int*   gen    = (const int*)d_in[1];
  const unsigned char* maskb = (const unsigned char*)d_in[2];
  const int*   req    = (const int*)d_in[3];
  float* out = (float*)d_out;

  int R = in_sizes[3];
  if (R >= 256 && (R & 3) == 0) R >>= 2;   // bytes -> elements

  int ml;
  if (in_sizes[0] == BB * VV * 4) {        // bytes mode
    ml = (in_sizes[2] == VV) ? 1 : 3;      // 128000 -> u8 ; 512000 -> 32-bit
  } else {
    ml = -1;
  }

  const size_t NEED = 8192 + (size_t)NWIN * EXC_CAP * sizeof(uint2);
  if (d_ws != nullptr && ws_size >= NEED) {
    unsigned* wsc = (unsigned*)d_ws;
    uint2*    wse = (uint2*)((char*)d_ws + 8192);
    if (ml == 1)
      enforce_fused<1><<<2 * NWIN, NT, 0, stream>>>(logits, gen, maskb, req, out, wsc, wse, R);
    else if (ml == 3)
      enforce_fused<3><<<2 * NWIN, NT, 0, stream>>>(logits, gen, maskb, req, out, wsc, wse, R);
    else
      enforce_fused<-1><<<2 * NWIN, NT, 0, stream>>>(logits, gen, maskb, req, out, wsc, wse, R);
    apply_exc<<<(NWIN + NT - 1) / NT, NT, 0, stream>>>(out, wsc, wse);
  } else {
    if (ml == 1)      enforce_mono<1><<<NWIN, NT, 0, stream>>>(logits, gen, maskb, req, out, R);
    else if (ml == 3) enforce_mono<3><<<NWIN, NT, 0, stream>>>(logits, gen, maskb, req, out, R);
    else              enforce_mono<-1><<<NWIN, NT, 0, stream>>>(logits, gen, maskb, req, out, R);
  }
}

// Round 16
// 134.632 us; speedup vs baseline: 1.0769x; 1.0769x over previous
//
#include <hip/hip_runtime.h>
#include <cstdint>
#include <cstddef>

#define BB 128
#define VV 128000
#define TT 4096
#define NWIN 2048            // windows = 128 rows x 16 slices
#define WVR (VV / 16)        // 8000 tokens per window
#define WHW (WVR / 4)        // 2000 packed words
#define NT 256
#define EXC_CAP 96

typedef float vf4 __attribute__((ext_vector_type(4)));

// Round-26 = round-23 resubmitted verbatim (third GPU acquisition timeout on
// this kernel — range-based role split still unmeasured; holding fixed).
// Round-23 = round-21 with ONE change: role split by BLOCK RANGE, not parity.
// r12 bench: enforce_fused 52 us (vs r16 mono ~40), occupancy 46%. Diagnosis:
// HW maps blocks to XCDs round-robin by blockIdx%8; role = L&1 put ALL stream
// blocks on even XCDs {0,2,4,6} and all hist blocks on odd ones — the stream
// ran on half the machine (52 ~= 2 x the expected 26 us), and win_decode's
// id&7 "XCD swizzle" was scrambled (true XCD = (2id+role)&7). The role-split
// hypothesis was never actually tested — it was confounded by XCD aliasing.
// Fix: blocks [0,NWIN) = stream (all 8 XCDs, launched first -> machine starts
// at full stream BW), [NWIN,2*NWIN) = hist (flow in as stream blocks retire).
// 2048 % 8 == 0 so win_decode's id&7 matches the true XCD for both roles.
// Exception machinery unchanged from r21 (passed correctness).
// SENT = 0xFF7F0000 (finite bf16 0xFF7F) — r1/r2 lessons. RINV <=1 ulp.

__device__ __forceinline__ void win_decode(int id, int& b, int& vbase) {
  // XCD-aware swizzle: 16 windows of a row land on one XCD (gen L2 locality)
  const int xcd = id & 7, q = id >> 3, s = q & 15;
  b = (q >> 4) * 8 + xcd;
  vbase = s * WVR;
}

__device__ __forceinline__ int block_detect(const unsigned char* maskb,
                                            unsigned* det, int tid) {
  if (tid == 0) *det = 0u;
  __syncthreads();
  const uint4* md = (const uint4*)maskb;
  unsigned a = 0u, c = 0u;
#pragma unroll
  for (int k = 0; k < 4; ++k) {          // 256 threads x 4 uint4 = 16 KB scan
    uint4 w = md[tid + k * NT];
    unsigned o = w.x | w.y | w.z | w.w;
    a |= o & 0x000000FFu;
    c |= o & 0xFFFFFF00u;
  }
  unsigned long long ba = __ballot(a != 0u);
  unsigned long long bc = __ballot(c != 0u);
  if ((tid & 63) == 0) {
    unsigned bits = (ba ? 1u : 0u) | (bc ? 2u : 0u);
    if (bits) atomicOr(det, bits);
  }
  __syncthreads();
  return (*det == 3u) ? 1 : 3;   // u8 vs 32-bit word mode
}

template<int ML>
__global__ __launch_bounds__(NT) void enforce_fused(
    const float* __restrict__ logits,
    const int*  __restrict__ gen,
    const unsigned char* __restrict__ maskb,
    const int*  __restrict__ req,
    float* __restrict__ out,
    unsigned* __restrict__ wsc,       // [NWIN] exception counts
    uint2*    __restrict__ wse,       // [NWIN][EXC_CAP] {idx-in-window, bits(val)}
    int R)
{
  __shared__ unsigned hist[WHW];   // 8 KB (hist role only)
  __shared__ uint2 exc[EXC_CAP];
  __shared__ unsigned nexc;
  const int tid = threadIdx.x;
  const int L   = blockIdx.x;      // 4096
  const bool is_stream = (L < NWIN);
  const int id  = is_stream ? L : (L - NWIN);
  int b, vbase; win_decode(id, b, vbase);

  int ml = ML;
  if constexpr (ML == -1) {
    __shared__ unsigned det;
    ml = block_detect(maskb, &det, tid);
  }

  const float SENT = __uint_as_float(0xFF7F0000u);
  const float RINV = 1.0f / 1.2f;
  auto forb1 = [&](int t) -> bool {
    if (ml == 1) return maskb[t] != 0;
    return ((const int*)maskb)[t] != 0;   // i32 1 / f32 1.0f both nonzero
  };

  if (is_stream) {
    // ================= STREAM ROLE: pure masked copy, x4 unroll =============
    const vf4* lrow = (const vf4*)(logits + (size_t)b * VV + vbase);
    vf4*       orow = (vf4*)(out + (size_t)b * VV + vbase);
    const unsigned* m8  = (const unsigned*)(maskb + vbase);
    const int4*     m32 = (const int4*)((const int*)maskb + vbase);
    auto lmask = [&](int i) -> unsigned {
      if (ml == 1) return m8[i];
      int4 m = m32[i];
      return (m.x ? 1u : 0u) | (m.y ? 0x100u : 0u) |
             (m.z ? 0x10000u : 0u) | (m.w ? 0x1000000u : 0u);
    };
    for (int i0 = tid; i0 < WHW; i0 += 4 * NT) {   // 2 outer iterations
      const int i1 = i0 + NT, i2 = i0 + 2 * NT, i3 = i0 + 3 * NT;
      const bool p1 = i1 < WHW, p2 = i2 < WHW, p3 = i3 < WHW;
      vf4 x0 = lrow[i0];           unsigned f0 = lmask(i0);
      vf4 x1 = {0,0,0,0}, x2 = {0,0,0,0}, x3 = {0,0,0,0};
      unsigned f1 = 0, f2 = 0, f3 = 0;
      if (p1) { x1 = lrow[i1]; f1 = lmask(i1); }
      if (p2) { x2 = lrow[i2]; f2 = lmask(i2); }
      if (p3) { x3 = lrow[i3]; f3 = lmask(i3); }
      vf4 r0, r1, r2, r3;
#pragma unroll
      for (int j = 0; j < 4; ++j) r0[j] = ((f0 >> (j*8)) & 0xFFu) ? SENT : x0[j];
      orow[i0] = r0;
      if (p1) {
#pragma unroll
        for (int j = 0; j < 4; ++j) r1[j] = ((f1 >> (j*8)) & 0xFFu) ? SENT : x1[j];
        orow[i1] = r1;
      }
      if (p2) {
#pragma unroll
        for (int j = 0; j < 4; ++j) r2[j] = ((f2 >> (j*8)) & 0xFFu) ? SENT : x2[j];
        orow[i2] = r2;
      }
      if (p3) {
#pragma unroll
        for (int j = 0; j < 4; ++j) r3[j] = ((f3 >> (j*8)) & 0xFFu) ? SENT : x3[j];
        orow[i3] = r3;
      }
    }
  } else {
    // ================= HIST ROLE: exceptions -> ws ==========================
    for (int i = tid; i < WHW; i += NT) hist[i] = 0u;
    if (tid == 0) nexc = 0u;
    __syncthreads();

    // gen scan; atomicAdd return catches the unique 2->3 transition.
    // Penalty value is a pure function of logits -> computable NOW.
    const int4* grow = (const int4*)(gen + b * TT);
    for (int i = tid; i < TT / 4; i += NT) {       // 4 iterations
      int4 g = grow[i];
      const int t4[4] = {g.x, g.y, g.z, g.w};
#pragma unroll
      for (int j = 0; j < 4; ++j) {
        const int t = t4[j];
        unsigned d = (unsigned)(t - vbase);
        if (d < (unsigned)WVR) {
          const unsigned sh = (d & 3u) * 8u;
          unsigned old = atomicAdd(&hist[d >> 2], 1u << sh);
          if (((old >> sh) & 0xFFu) == 2u && !forb1(t)) {
            float v  = logits[(size_t)b * VV + t];
            float pv = (v > 0.0f) ? v * RINV : v * 1.2f;
            unsigned k = atomicAdd(&nexc, 1u);
            if (k < EXC_CAP) exc[k] = make_uint2(d, __float_as_uint(pv));
          }
        }
      }
    }
    __syncthreads();   // cnt final before boost check

    // boosts: req tokens in-window, cnt==0, allowed. Dedup to first
    // occurrence; value = logits + 5*multiplicity (matches reference
    // duplicate scatter-add).
    for (int r = tid; r < R; r += NT) {
      const int t = req[r];
      unsigned d = (unsigned)(t - vbase);
      if (d < (unsigned)WVR) {
        bool first = true; int mult = 0;
        for (int j = 0; j < R; ++j) {
          if (req[j] == t) { if (j < r) first = false; ++mult; }
        }
        if (first) {
          unsigned cnt = (hist[d >> 2] >> ((d & 3u) * 8u)) & 0xFFu;
          if (cnt == 0u && !forb1(t)) {
            float v = logits[(size_t)b * VV + t] + 5.0f * (float)mult;
            unsigned k = atomicAdd(&nexc, 1u);
            if (k < EXC_CAP) exc[k] = make_uint2(d, __float_as_uint(v));
          }
        }
      }
    }
    __syncthreads();

    unsigned n = nexc < EXC_CAP ? nexc : EXC_CAP;
    if (tid == 0) wsc[id] = n;
    for (unsigned k = tid; k < n; k += NT)
      wse[(size_t)id * EXC_CAP + k] = exc[k];
  }
}

__global__ __launch_bounds__(NT) void apply_exc(
    float* __restrict__ out,
    const unsigned* __restrict__ wsc,
    const uint2* __restrict__ wse)
{
  const int w = blockIdx.x * NT + threadIdx.x;
  if (w >= NWIN) return;
  int b, vbase; win_decode(w, b, vbase);
  unsigned n = wsc[w]; if (n > EXC_CAP) n = EXC_CAP;
  const uint2* e = wse + (size_t)w * EXC_CAP;
  for (unsigned k = 0; k < n; ++k) {
    uint2 q = e[k];
    out[(size_t)b * VV + vbase + q.x] = __uint_as_float(q.y);
  }
}

// ---------------- fallback monolith (r16, measured 123.9 total) -------------
template<int ML>
__global__ __launch_bounds__(NT) void enforce_mono(
    const float* __restrict__ logits,
    const int*  __restrict__ gen,
    const unsigned char* __restrict__ maskb,
    const int*  __restrict__ req,
    float* __restrict__ out,
    int R)
{
  __shared__ unsigned hist[WHW];
  __shared__ int cand[64];
  __shared__ unsigned ncand;
  const int tid = threadIdx.x;
  int b, vbase; win_decode(blockIdx.x, b, vbase);

  int ml = ML;
  if constexpr (ML == -1) {
    __shared__ unsigned det;
    ml = block_detect(maskb, &det, tid);
  }
  for (int i = tid; i < WHW; i += NT) hist[i] = 0u;
  if (tid == 0) ncand = 0u;
  __syncthreads();

  const float SENT = __uint_as_float(0xFF7F0000u);
  const float RINV = 1.0f / 1.2f;
  auto forb1 = [&](int t) -> bool {
    if (ml == 1) return maskb[t] != 0;
    return ((const int*)maskb)[t] != 0;
  };
  const vf4* lrow = (const vf4*)(logits + (size_t)b * VV + vbase);
  vf4*       orow = (vf4*)(out + (size_t)b * VV + vbase);
  const unsigned* m8  = (const unsigned*)(maskb + vbase);
  const int4*     m32 = (const int4*)((const int*)maskb + vbase);
  auto lmask = [&](int i) -> unsigned {
    if (ml == 1) return m8[i];
    int4 m = m32[i];
    return (m.x ? 1u : 0u) | (m.y ? 0x100u : 0u) |
           (m.z ? 0x10000u : 0u) | (m.w ? 0x1000000u : 0u);
  };
  for (int i0 = tid; i0 < WHW; i0 += 2 * NT) {
    const int i1 = i0 + NT;
    const bool p1 = (i1 < WHW);
    vf4 x0 = lrow[i0]; unsigned f0 = lmask(i0);
    vf4 x1 = {0,0,0,0}; unsigned f1 = 0u;
    if (p1) { x1 = lrow[i1]; f1 = lmask(i1); }
    vf4 r0, r1;
#pragma unroll
    for (int j = 0; j < 4; ++j) r0[j] = ((f0 >> (j*8)) & 0xFFu) ? SENT : x0[j];
    orow[i0] = r0;
    if (p1) {
#pragma unroll
      for (int j = 0; j < 4; ++j) r1[j] = ((f1 >> (j*8)) & 0xFFu) ? SENT : x1[j];
      orow[i1] = r1;
    }
  }
  const int4* grow = (const int4*)(gen + b * TT);
  for (int i = tid; i < TT / 4; i += NT) {
    int4 g = grow[i];
    const int t4[4] = {g.x, g.y, g.z, g.w};
#pragma unroll
    for (int j = 0; j < 4; ++j) {
      const int t = t4[j];
      unsigned d = (unsigned)(t - vbase);
      if (d < (unsigned)WVR) {
        const unsigned sh = (d & 3u) * 8u;
        unsigned old = atomicAdd(&hist[d >> 2], 1u << sh);
        if (((old >> sh) & 0xFFu) == 2u) {
          unsigned k = atomicAdd(&ncand, 1u);
          if (k < 64u) cand[k] = t;
        }
      }
    }
  }
  __syncthreads();
  const unsigned nc = ncand < 64u ? ncand : 64u;
  for (unsigned k = tid; k < nc; k += NT) {
    const int t = cand[k];
    if (!forb1(t)) {
      float v = logits[(size_t)b * VV + t];
      out[(size_t)b * VV + t] = (v > 0.0f) ? v * RINV : v * 1.2f;
    }
  }
  for (int r = tid; r < R; r += NT) {
    const int t = req[r];
    unsigned d = (unsigned)(t - vbase);
    if (d < (unsigned)WVR) {
      unsigned cnt = (hist[d >> 2] >> ((d & 3u) * 8u)) & 0xFFu;
      if (cnt == 0u && !forb1(t))
        atomicAdd(out + (size_t)b * VV + t, 5.0f);
    }
  }
}

extern "C" void kernel_launch(void* const* d_in, const int* in_sizes, int n_in,
                              void* d_out, int out_size, void* d_ws, size_t ws_size,
                              hipStream_t stream) {
  const float* logits = (const float*)d_in[0];
  const int*   gen    = (const int*)d_in[1];
  const unsigned char* maskb = (const unsigned char*)d_in[2];
  const int*   req    = (const int*)d_in[3];
  float* out = (float*)d_out;

  int R = in_sizes[3];
  if (R >= 256 && (R & 3) == 0) R >>= 2;   // bytes -> elements

  int ml;
  if (in_sizes[0] == BB * VV * 4) {        // bytes mode
    ml = (in_sizes[2] == VV) ? 1 : 3;      // 128000 -> u8 ; 512000 -> 32-bit
  } else {
    ml = -1;
  }

  const size_t NEED = 8192 + (size_t)NWIN * EXC_CAP * sizeof(uint2);
  if (d_ws != nullptr && ws_size >= NEED) {
    unsigned* wsc = (unsigned*)d_ws;
    uint2*    wse = (uint2*)((char*)d_ws + 8192);
    if (ml == 1)
      enforce_fused<1><<<2 * NWIN, NT, 0, stream>>>(logits, gen, maskb, req, out, wsc, wse, R);
    else if (ml == 3)
      enforce_fused<3><<<2 * NWIN, NT, 0, stream>>>(logits, gen, maskb, req, out, wsc, wse, R);
    else
      enforce_fused<-1><<<2 * NWIN, NT, 0, stream>>>(logits, gen, maskb, req, out, wsc, wse, R);
    apply_exc<<<(NWIN + NT - 1) / NT, NT, 0, stream>>>(out, wsc, wse);
  } else {
    if (ml == 1)      enforce_mono<1><<<NWIN, NT, 0, stream>>>(logits, gen, maskb, req, out, R);
    else if (ml == 3) enforce_mono<3><<<NWIN, NT, 0, stream>>>(logits, gen, maskb, req, out, R);
    else              enforce_mono<-1><<<NWIN, NT, 0, stream>>>(logits, gen, maskb, req, out, R);
  }
}